// Round 17
// baseline (127.174 us; speedup 1.0000x reference)
//
#include <hip/hip_runtime.h>

#define Bx 32
#define Nx 512
#define Ex 4
#define Fx 128
#define Gx 64
#define HIDx 256
#define EMBx 128
#define NEDGE 8192

typedef __attribute__((ext_vector_type(8))) short bf16x8;
typedef __attribute__((ext_vector_type(4))) float f32x4;

#define L2E 1.44269504f

__device__ __forceinline__ ushort f2bf(float x) {
    unsigned int u = __float_as_uint(x);
    u += 0x7fffu + ((u >> 16) & 1u);
    return (ushort)(u >> 16);
}
__device__ __forceinline__ float bf2f(ushort h) {
    return __uint_as_float(((unsigned int)h) << 16);
}

// ---- K0b: edge binning into 4 x 128-row segments + weight transpose/cast ---
__global__ __launch_bounds__(512) void k0b(const int* __restrict__ edges,
                                           const float* __restrict__ w0,
                                           const float* __restrict__ w1f,
                                           const float* __restrict__ Wsf,
                                           ushort* __restrict__ W0T,
                                           ushort* __restrict__ W1T,
                                           ushort* __restrict__ WsT,
                                           ushort* __restrict__ binned,
                                           int* __restrict__ offs) {
    __shared__ int hist8[8][4];
    __shared__ int offl[5];
    __shared__ int cur[4];
    int blk = blockIdx.x, tid = threadIdx.x;
    if (blk < 128) {
        int wave = tid >> 6;
        if (tid < 32) ((int*)hist8)[tid] = 0;
        __syncthreads();
        const int4* s4p = (const int4*)(edges + (size_t)blk * 2 * NEDGE);
        const int4* d4p = (const int4*)(edges + (size_t)blk * 2 * NEDGE + NEDGE);
        for (int i = tid; i < NEDGE / 4; i += 512) {
            int4 s4 = s4p[i];
            atomicAdd(&hist8[wave][s4.x >> 7], 1);
            atomicAdd(&hist8[wave][s4.y >> 7], 1);
            atomicAdd(&hist8[wave][s4.z >> 7], 1);
            atomicAdd(&hist8[wave][s4.w >> 7], 1);
        }
        __syncthreads();
        if (tid == 0) {
            int run = 0;
            for (int t = 0; t < 4; ++t) {
                offl[t] = run;
                int s = 0;
                #pragma unroll
                for (int w = 0; w < 8; ++w) s += hist8[w][t];
                run += s;
            }
            offl[4] = run;
            for (int t = 0; t <= 4; ++t) offs[blk * 5 + t] = offl[t];
        }
        __syncthreads();
        if (tid < 4) cur[tid] = offl[tid];
        __syncthreads();
        ushort* bout = binned + (size_t)blk * NEDGE;
        for (int i = tid; i < NEDGE / 4; i += 512) {
            int4 s4 = s4p[i]; int4 d4 = d4p[i];
            int ss[4] = {s4.x, s4.y, s4.z, s4.w};
            int dd[4] = {d4.x, d4.y, d4.z, d4.w};
            #pragma unroll
            for (int u = 0; u < 4; ++u) {
                int t = ss[u] >> 7;
                int pos = atomicAdd(&cur[t], 1);
                bout[pos] = (ushort)(((ss[u] & 127) << 9) | dd[u]);
            }
        }
    } else if (blk < 256) {
        int idx = (blk - 128) * 512 + tid;
        int j = idx >> 8, k = idx & 255;
        W0T[j * HIDx + k] = f2bf(w0[k * HIDx + j]);
    } else if (blk < 320) {
        int idx = (blk - 256) * 512 + tid;
        int j = idx >> 8, k = idx & 255;
        W1T[j * HIDx + k] = f2bf(w1f[k * EMBx + j]);
    } else {
        int idx = (blk - 320) * 512 + tid;
        int eg = idx >> 7, f = idx & 127;
        WsT[eg * Fx + f] = f2bf(Wsf[((eg >> 6) * Fx + f) * Gx + (eg & 63)]);
    }
}

// ---- K1: Whb[be,g,m] = bf16(X @ Ws) via MFMA; w1/w2 = Wh . a ---------------
__global__ __launch_bounds__(256) void k1_wh(const float* __restrict__ X,
                                             const ushort* __restrict__ WsT,
                                             const float* __restrict__ a,
                                             ushort* __restrict__ Whb,
                                             float* __restrict__ w1,
                                             float* __restrict__ w2) {
    __shared__ ushort sXb[64 * 128];   // 16KB, XOR-swizzled bf16 A tile
    int id = blockIdx.x;
    int e = id & 3;
    int rest = id >> 2;
    int tile = rest & 7;
    int b = rest >> 3;
    int be = b * 4 + e;
    int n0 = tile * 64;
    int tid = threadIdx.x;
    for (int i = tid; i < 2048; i += 256) {
        int row = i >> 5, kq = i & 31;
        float4 xv = *(const float4*)&X[(size_t)(b * Nx + n0 + row) * Fx + kq * 4];
        ushort4 hv;
        hv.x = f2bf(xv.x); hv.y = f2bf(xv.y); hv.z = f2bf(xv.z); hv.w = f2bf(xv.w);
        unsigned int byteo = ((unsigned int)(row * 256 + kq * 8)) ^ (((unsigned int)(row & 7)) << 4);
        *(ushort4*)((char*)sXb + byteo) = hv;
    }
    __syncthreads();
    int wave = tid >> 6, lane = tid & 63;
    int arow = lane & 15, kg = lane >> 4;
    int row = wave * 16 + arow;
    f32x4 acc[4];
    #pragma unroll
    for (int t = 0; t < 4; ++t) acc[t] = (f32x4){0.f, 0.f, 0.f, 0.f};
    const ushort* WT = WsT + e * Gx * Fx;   // [g][f]
    unsigned int aswz = ((unsigned int)(row & 7)) << 4;
    #pragma unroll
    for (int ks = 0; ks < 4; ++ks) {
        unsigned int abyte = ((unsigned int)(row * 256 + ks * 64 + kg * 16)) ^ aswz;
        bf16x8 af = *(const bf16x8*)((const char*)sXb + abyte);
        #pragma unroll
        for (int jt = 0; jt < 4; ++jt) {
            bf16x8 bf = *(const bf16x8*)&WT[(size_t)(jt * 16 + arow) * Fx + ks * 32 + kg * 8];
            acc[jt] = __builtin_amdgcn_mfma_f32_16x16x32_bf16(af, bf, acc[jt], 0, 0, 0);
        }
    }
    float a1v[4], a2v[4];
    #pragma unroll
    for (int jt = 0; jt < 4; ++jt) {
        a1v[jt] = a[e * 2 * Gx + jt * 16 + arow];
        a2v[jt] = a[e * 2 * Gx + Gx + jt * 16 + arow];
    }
    int m0 = n0 + wave * 16 + kg * 4;
    #pragma unroll
    for (int jt = 0; jt < 4; ++jt) {
        int g = jt * 16 + arow;
        ushort4 v;
        v.x = f2bf(acc[jt][0]); v.y = f2bf(acc[jt][1]);
        v.z = f2bf(acc[jt][2]); v.w = f2bf(acc[jt][3]);
        *(ushort4*)&Whb[((size_t)be * Gx + g) * Nx + m0] = v;
    }
    #pragma unroll
    for (int reg = 0; reg < 4; ++reg) {
        float p1 = acc[0][reg] * a1v[0] + acc[1][reg] * a1v[1] + acc[2][reg] * a1v[2] + acc[3][reg] * a1v[3];
        float p2 = acc[0][reg] * a2v[0] + acc[1][reg] * a2v[1] + acc[2][reg] * a2v[2] + acc[3][reg] * a2v[3];
        #pragma unroll
        for (int off = 1; off < 16; off <<= 1) {
            p1 += __shfl_xor(p1, off, 64);
            p2 += __shfl_xor(p2, off, 64);
        }
        if (arow == 0) {
            w1[be * Nx + m0 + reg] = p1;
            w2[be * Nx + m0 + reg] = p2;
        }
    }
}

// ---- K2: 128-row tiles, 1024 threads; owner compaction -> MFMA PV ----------
__global__ __launch_bounds__(1024) void k2_att(const ushort* __restrict__ binned,
                                               const int* __restrict__ offs,
                                               const ushort* __restrict__ Whb,
                                               const float* __restrict__ w1g,
                                               const float* __restrict__ w2g,
                                               ushort* __restrict__ Hb) {
    __shared__ ushort P[128 * 512];         // 128KB; first 67584B doubles as cnt
    __shared__ float sw2[512];              // pre-scaled by log2e
    __shared__ float sw1[128];
    __shared__ float sinv[128];
    __shared__ float rowsum[128];
    __shared__ int   rowK[128];
    __shared__ ushort olist[8192];          // compacted distinct (r<<9|d)
    __shared__ int ocnt;
    unsigned int* cnt = (unsigned int*)P;   // [128][132]
    int be = blockIdx.x; int b = be >> 2; int e = be & 3;
    int tile = blockIdx.y; int n0 = tile * 128;
    int tid = threadIdx.x;
    for (int i = tid; i < 128 * 132; i += 1024) cnt[i] = 0u;
    if (tid < 512) sw2[tid] = w2g[be * Nx + tid] * L2E;
    if (tid < 128) {
        sw1[tid] = w1g[be * Nx + n0 + tid] * L2E;
        rowsum[tid] = 0.f; rowK[tid] = 0;
    }
    if (tid == 0) ocnt = 0;
    __syncthreads();
    // phase 2: scatter binned edges; wave-aggregated append of first-touches
    int t0 = offs[be * 5 + tile], t1 = offs[be * 5 + tile + 1];
    const ushort* bin = binned + (size_t)be * NEDGE;
    int lane = tid & 63;
    for (int i = t0 + tid; i < t1; i += 1024) {
        unsigned int pk = bin[i];
        unsigned int sh = (pk & 3u) * 8;
        unsigned int old = atomicAdd(&cnt[(pk >> 9) * 132 + ((pk & 511u) >> 2)], 1u << sh);
        bool own = ((old >> sh) & 255u) == 0u;
        unsigned long long m = __ballot(own);
        if (m) {
            int leader = __ffsll((long long)m) - 1;
            int base = 0;
            if (lane == leader) base = atomicAdd(&ocnt, __popcll(m));
            base = __shfl(base, leader, 64);
            if (own) {
                int ix = base + __popcll(m & ((1ull << lane) - 1ull));
                if (ix < 8192) olist[ix] = (ushort)pk;
            }
        }
    }
    __syncthreads();
    // phase 3a: process owned entries (<=8/thread, static regs)
    int tot = ocnt; if (tot > 8192) tot = 8192;
    const unsigned char* cb = (const unsigned char*)cnt;
    ushort pbv[8]; int pkv[8];
    #pragma unroll
    for (int u = 0; u < 8; ++u) {
        int i = tid + u * 1024;
        bool v = i < tot;
        int pk = v ? (int)olist[i] : 0;
        int r = pk >> 9, d = pk & 511;
        float c = (float)cb[r * 528 + d];
        float ew = __builtin_exp2f(fminf((sw1[r] + sw2[d]) * c, 120.f));
        if (v) {
            atomicAdd(&rowsum[r], ew);
            atomicAdd(&rowK[r], 1);
        }
        pbv[u] = f2bf(ew * c);
        pkv[u] = v ? pk : -1;
    }
    __syncthreads();   // cnt fully consumed; P may be overwritten
    // phase 3b: zero P (128B per thread)
    {
        uint4 z = {0u, 0u, 0u, 0u};
        #pragma unroll
        for (int u = 0; u < 8; ++u)
            *(uint4*)((char*)P + tid * 128 + u * 16) = z;
    }
    __syncthreads();
    // phase 3c: scatter bf16 weights (unique (r,d) -> race-free); sinv
    #pragma unroll
    for (int u = 0; u < 8; ++u) {
        if (pkv[u] >= 0) {
            int r = pkv[u] >> 9, d = pkv[u] & 511;
            unsigned int byteo = ((unsigned int)(r * 1024 + d * 2)) ^ (((unsigned int)(r & 7)) << 4);
            *(ushort*)((char*)P + byteo) = pbv[u];
        }
    }
    if (tid < 128) sinv[tid] = 1.f / (rowsum[tid] + (float)(Nx - rowK[tid]));
    __syncthreads();
    // phase 4: H-tile = P @ Whb; 16 waves x 2 sub-tiles (B fragments reused)
    int wave = tid >> 6;
    int wr2 = wave >> 2, wc = wave & 3;     // wr2 in [0,4), wc in [0,4)
    int rowa = wr2 * 32 + (lane & 15);
    int rowb = rowa + 16;
    int kgrp = lane >> 4;
    f32x4 acca = {0.f, 0.f, 0.f, 0.f};
    f32x4 accb = {0.f, 0.f, 0.f, 0.f};
    const ushort* WB = Whb + (size_t)be * Gx * Nx;
    int g0 = wc * 16 + (lane & 15);
    const ushort* Bp = WB + (size_t)g0 * Nx + kgrp * 8;
    unsigned int aswza = ((unsigned int)(rowa & 7)) << 4;
    __builtin_amdgcn_s_setprio(1);
    #pragma unroll
    for (int ks = 0; ks < 16; ++ks) {
        bf16x8 bfv = *(const bf16x8*)(Bp + ks * 32);
        unsigned int ka = (unsigned int)(ks * 64 + kgrp * 16);
        unsigned int offa = ((unsigned int)(rowa * 1024) + ka) ^ aswza;
        unsigned int offb = ((unsigned int)(rowb * 1024) + ka) ^ aswza;
        bf16x8 afa = *(const bf16x8*)((const char*)P + offa);
        bf16x8 afb = *(const bf16x8*)((const char*)P + offb);
        acca = __builtin_amdgcn_mfma_f32_16x16x32_bf16(afa, bfv, acca, 0, 0, 0);
        accb = __builtin_amdgcn_mfma_f32_16x16x32_bf16(afb, bfv, accb, 0, 0, 0);
    }
    __builtin_amdgcn_s_setprio(0);
    #pragma unroll
    for (int reg = 0; reg < 4; ++reg) {
        int ra = n0 + wr2 * 32 + kgrp * 4 + reg;
        float iva = sinv[wr2 * 32 + kgrp * 4 + reg];
        float ivb = sinv[wr2 * 32 + 16 + kgrp * 4 + reg];
        Hb[((size_t)(b * Nx) + ra) * (Ex * Gx) + e * Gx + wc * 16 + (lane & 15)] =
            f2bf(acca[reg] * iva);
        Hb[((size_t)(b * Nx) + ra + 16) * (Ex * Gx) + e * Gx + wc * 16 + (lane & 15)] =
            f2bf(accb[reg] * ivb);
    }
}

// ---- K3: h_pre = bf16(Hb @ W0 + b) via MFMA; fp32 BN partials --------------
__global__ __launch_bounds__(256) void k3_lin0(const ushort* __restrict__ Hb,
                                               const ushort* __restrict__ W0T,
                                               const float* __restrict__ lin0_b,
                                               ushort* __restrict__ h_pre,
                                               float* __restrict__ partials) {
    __shared__ float red_s[2][256], red_q[2][256];
    int tid = threadIdx.x, wave = tid >> 6, lane = tid & 63;
    int wr = wave >> 1, wc = wave & 1;
    int row0 = blockIdx.x * 32 + wr * 16;
    int arow = lane & 15, kg = lane >> 4;
    const ushort* A = Hb + (size_t)(row0 + arow) * HIDx;
    f32x4 acc[8];
    #pragma unroll
    for (int t = 0; t < 8; ++t) acc[t] = (f32x4){0.f, 0.f, 0.f, 0.f};
    #pragma unroll
    for (int ks = 0; ks < 8; ++ks) {
        int k0 = ks * 32 + kg * 8;
        bf16x8 af = *(const bf16x8*)&A[k0];
        #pragma unroll
        for (int jt = 0; jt < 8; ++jt) {
            bf16x8 bf = *(const bf16x8*)&W0T[(size_t)(wc * 128 + jt * 16 + arow) * HIDx + k0];
            acc[jt] = __builtin_amdgcn_mfma_f32_16x16x32_bf16(af, bf, acc[jt], 0, 0, 0);
        }
    }
    #pragma unroll
    for (int jt = 0; jt < 8; ++jt) {
        int col = wc * 128 + jt * 16 + arow;
        float b = lin0_b[col];
        float s = 0.f, q = 0.f;
        #pragma unroll
        for (int reg = 0; reg < 4; ++reg) {
            float v = acc[jt][reg] + b;
            h_pre[(size_t)(row0 + kg * 4 + reg) * HIDx + col] = f2bf(v);
            s += v; q += v * v;
        }
        s += __shfl_xor(s, 16, 64); s += __shfl_xor(s, 32, 64);
        q += __shfl_xor(q, 16, 64); q += __shfl_xor(q, 32, 64);
        if (lane < 16) { red_s[wr][col] = s; red_q[wr][col] = q; }
    }
    __syncthreads();
    int j = tid;
    partials[(size_t)blockIdx.x * 2 * HIDx + j] = red_s[0][j] + red_s[1][j];
    partials[(size_t)blockIdx.x * 2 * HIDx + HIDx + j] = red_q[0][j] + red_q[1][j];
}

// ---- K3b: finalize BN stats -> scale/bias ----------------------------------
__global__ __launch_bounds__(256) void k3b_stats(const float* __restrict__ partials,
                                                 const float* __restrict__ gamma,
                                                 const float* __restrict__ beta,
                                                 float* __restrict__ sb) {
    __shared__ float rs[8][32], rq[8][32];
    int jl = threadIdx.x & 31, sl = threadIdx.x >> 5;
    int j = blockIdx.x * 32 + jl;
    float s = 0.f, q = 0.f;
    for (int blk = sl; blk < 512; blk += 8) {
        s += partials[blk * 512 + j];
        q += partials[blk * 512 + 256 + j];
    }
    rs[sl][jl] = s; rq[sl][jl] = q;
    __syncthreads();
    if (threadIdx.x < 32) {
        float S = 0.f, Q = 0.f;
        #pragma unroll
        for (int t = 0; t < 8; ++t) { S += rs[t][jl]; Q += rq[t][jl]; }
        const float invM = 1.f / 16384.f;
        float mu = S * invM;
        float var = fmaxf(Q * invM - mu * mu, 0.f);
        float sc = gamma[j] * rsqrtf(var + 1e-5f);
        sb[j] = sc;
        sb[256 + j] = beta[j] - mu * sc;
    }
}

// ---- K4: out = elu(bn(h_pre)) @ W1 + b via MFMA ----------------------------
__global__ __launch_bounds__(256) void k4_lin1(const ushort* __restrict__ h_pre,
                                               const float* __restrict__ sb,
                                               const ushort* __restrict__ W1T,
                                               const float* __restrict__ lin1_b,
                                               float* __restrict__ out) {
    int tid = threadIdx.x, wave = tid >> 6, lane = tid & 63;
    int wr = wave >> 1, wc = wave & 1;
    int row0 = blockIdx.x * 32 + wr * 16;
    int arow = lane & 15, kg = lane >> 4;
    const ushort* A = h_pre + (size_t)(row0 + arow) * HIDx;
    f32x4 acc[4];
    #pragma unroll
    for (int t = 0; t < 4; ++t) acc[t] = (f32x4){0.f, 0.f, 0.f, 0.f};
    #pragma unroll
    for (int ks = 0; ks < 8; ++ks) {
        int k0 = ks * 32 + kg * 8;
        bf16x8 hv = *(const bf16x8*)&A[k0];
        float4 sc0 = *(const float4*)&sb[k0];
        float4 sc1 = *(const float4*)&sb[k0 + 4];
        float4 bi0 = *(const float4*)&sb[256 + k0];
        float4 bi1 = *(const float4*)&sb[256 + k0 + 4];
        float scv[8] = {sc0.x, sc0.y, sc0.z, sc0.w, sc1.x, sc1.y, sc1.z, sc1.w};
        float biv[8] = {bi0.x, bi0.y, bi0.z, bi0.w, bi1.x, bi1.y, bi1.z, bi1.w};
        bf16x8 af;
        #pragma unroll
        for (int u = 0; u < 8; ++u) {
            float v = bf2f((ushort)hv[u]) * scv[u] + biv[u];
            v = v > 0.f ? v : expm1f(v);
            af[u] = (short)f2bf(v);
        }
        #pragma unroll
        for (int jt = 0; jt < 4; ++jt) {
            bf16x8 bf = *(const bf16x8*)&W1T[(size_t)(wc * 64 + jt * 16 + arow) * HIDx + k0];
            acc[jt] = __builtin_amdgcn_mfma_f32_16x16x32_bf16(af, bf, acc[jt], 0, 0, 0);
        }
    }
    #pragma unroll
    for (int jt = 0; jt < 4; ++jt) {
        int col = wc * 64 + jt * 16 + arow;
        float b = lin1_b[col];
        #pragma unroll
        for (int reg = 0; reg < 4; ++reg)
            out[(size_t)(row0 + kg * 4 + reg) * EMBx + col] = acc[jt][reg] + b;
    }
}

extern "C" void kernel_launch(void* const* d_in, const int* in_sizes, int n_in,
                              void* d_out, int out_size, void* d_ws, size_t ws_size,
                              hipStream_t stream) {
    const float* X      = (const float*)d_in[0];
    const int*   edges  = (const int*)d_in[1];
    const float* Ws     = (const float*)d_in[2];
    const float* a      = (const float*)d_in[3];
    const float* lin0_w = (const float*)d_in[4];
    const float* lin0_b = (const float*)d_in[5];
    const float* gamma  = (const float*)d_in[6];
    const float* beta   = (const float*)d_in[7];
    const float* lin1_w = (const float*)d_in[8];
    const float* lin1_b = (const float*)d_in[9];
    float* ws = (float*)d_ws;

    ushort* Whb     = (ushort*)ws;
    ushort* h_pre   = (ushort*)ws;
    ushort* binned  = (ushort*)ws + 4194304;
    int*    offs    = (int*)(ws + 2621440);
    ushort* Hb      = (ushort*)(ws + 4194304);
    float*  w1      = ws + 8388608;              // 65,536
    float*  w2      = ws + 8454144;              // 65,536
    float*  partials= ws + 8519680;              // 262,144
    float*  sb      = ws + 8781824;              // 512
    ushort* WsT     = (ushort*)(ws + 8782336);   // 32,768 ushorts
    ushort* W0T     = (ushort*)(ws + 8798720);   // 65,536 ushorts
    ushort* W1T     = (ushort*)(ws + 8831488);   // 32,768 ushorts
    float*  out     = (float*)d_out;

    k0b    <<<dim3(384), 512, 0, stream>>>(edges, lin0_w, lin1_w, Ws, W0T, W1T, WsT, binned, offs);
    k1_wh  <<<dim3(1024), 256, 0, stream>>>(X, WsT, a, Whb, w1, w2);
    k2_att <<<dim3(Bx * Ex, Nx / 128), 1024, 0, stream>>>(binned, offs, Whb, w1, w2, Hb);
    k3_lin0<<<dim3(512), 256, 0, stream>>>(Hb, W0T, lin0_b, h_pre, partials);
    k3b_stats<<<8, 256, 0, stream>>>(partials, gamma, beta, sb);
    k4_lin1<<<dim3(512), 256, 0, stream>>>(h_pre, sb, W1T, lin1_b, out);
}

// Round 18
// 121.235 us; speedup vs baseline: 1.0490x; 1.0490x over previous
//
#include <hip/hip_runtime.h>

#define Bx 32
#define Nx 512
#define Ex 4
#define Fx 128
#define Gx 64
#define HIDx 256
#define EMBx 128
#define NEDGE 8192

typedef __attribute__((ext_vector_type(8))) short bf16x8;
typedef __attribute__((ext_vector_type(4))) float f32x4;

#define L2E 1.44269504f

__device__ __forceinline__ ushort f2bf(float x) {
    unsigned int u = __float_as_uint(x);
    u += 0x7fffu + ((u >> 16) & 1u);
    return (ushort)(u >> 16);
}
__device__ __forceinline__ float bf2f(ushort h) {
    return __uint_as_float(((unsigned int)h) << 16);
}

// ---- K0b: edge binning into 8 x 64-row segments + weight transpose/cast ----
__global__ __launch_bounds__(512) void k0b(const int* __restrict__ edges,
                                           const float* __restrict__ w0,
                                           const float* __restrict__ w1f,
                                           const float* __restrict__ Wsf,
                                           ushort* __restrict__ W0T,
                                           ushort* __restrict__ W1T,
                                           ushort* __restrict__ WsT,
                                           ushort* __restrict__ binned,
                                           int* __restrict__ offs) {
    __shared__ int hist8[8][8];
    __shared__ int offl[9];
    __shared__ int cur[8];
    int blk = blockIdx.x, tid = threadIdx.x;
    if (blk < 128) {
        int wave = tid >> 6;
        if (tid < 64) ((int*)hist8)[tid] = 0;
        __syncthreads();
        const int4* s4p = (const int4*)(edges + (size_t)blk * 2 * NEDGE);
        const int4* d4p = (const int4*)(edges + (size_t)blk * 2 * NEDGE + NEDGE);
        for (int i = tid; i < NEDGE / 4; i += 512) {
            int4 s4 = s4p[i];
            atomicAdd(&hist8[wave][s4.x >> 6], 1);
            atomicAdd(&hist8[wave][s4.y >> 6], 1);
            atomicAdd(&hist8[wave][s4.z >> 6], 1);
            atomicAdd(&hist8[wave][s4.w >> 6], 1);
        }
        __syncthreads();
        if (tid == 0) {
            int run = 0;
            for (int t = 0; t < 8; ++t) {
                offl[t] = run;
                int s = 0;
                #pragma unroll
                for (int w = 0; w < 8; ++w) s += hist8[w][t];
                run += s;
            }
            offl[8] = run;
            for (int t = 0; t <= 8; ++t) offs[blk * 9 + t] = offl[t];
        }
        __syncthreads();
        if (tid < 8) cur[tid] = offl[tid];
        __syncthreads();
        ushort* bout = binned + (size_t)blk * NEDGE;
        for (int i = tid; i < NEDGE / 4; i += 512) {
            int4 s4 = s4p[i]; int4 d4 = d4p[i];
            int ss[4] = {s4.x, s4.y, s4.z, s4.w};
            int dd[4] = {d4.x, d4.y, d4.z, d4.w};
            #pragma unroll
            for (int u = 0; u < 4; ++u) {
                int t = ss[u] >> 6;
                int pos = atomicAdd(&cur[t], 1);
                bout[pos] = (ushort)(((ss[u] & 63) << 9) | dd[u]);
            }
        }
    } else if (blk < 256) {
        int idx = (blk - 128) * 512 + tid;
        int j = idx >> 8, k = idx & 255;
        W0T[j * HIDx + k] = f2bf(w0[k * HIDx + j]);
    } else if (blk < 320) {
        int idx = (blk - 256) * 512 + tid;
        int j = idx >> 8, k = idx & 255;
        W1T[j * HIDx + k] = f2bf(w1f[k * EMBx + j]);
    } else {
        int idx = (blk - 320) * 512 + tid;
        int eg = idx >> 7, f = idx & 127;
        WsT[eg * Fx + f] = f2bf(Wsf[((eg >> 6) * Fx + f) * Gx + (eg & 63)]);
    }
}

// ---- K1: Whb[be,g,m] = bf16(X @ Ws) via MFMA; w1/w2 = Wh . a ---------------
__global__ __launch_bounds__(256) void k1_wh(const float* __restrict__ X,
                                             const ushort* __restrict__ WsT,
                                             const float* __restrict__ a,
                                             ushort* __restrict__ Whb,
                                             float* __restrict__ w1,
                                             float* __restrict__ w2) {
    __shared__ ushort sXb[64 * 128];   // 16KB, XOR-swizzled bf16 A tile
    int id = blockIdx.x;
    int e = id & 3;
    int rest = id >> 2;
    int tile = rest & 7;
    int b = rest >> 3;
    int be = b * 4 + e;
    int n0 = tile * 64;
    int tid = threadIdx.x;
    for (int i = tid; i < 2048; i += 256) {
        int row = i >> 5, kq = i & 31;
        float4 xv = *(const float4*)&X[(size_t)(b * Nx + n0 + row) * Fx + kq * 4];
        ushort4 hv;
        hv.x = f2bf(xv.x); hv.y = f2bf(xv.y); hv.z = f2bf(xv.z); hv.w = f2bf(xv.w);
        unsigned int byteo = ((unsigned int)(row * 256 + kq * 8)) ^ (((unsigned int)(row & 7)) << 4);
        *(ushort4*)((char*)sXb + byteo) = hv;
    }
    __syncthreads();
    int wave = tid >> 6, lane = tid & 63;
    int arow = lane & 15, kg = lane >> 4;
    int row = wave * 16 + arow;
    f32x4 acc[4];
    #pragma unroll
    for (int t = 0; t < 4; ++t) acc[t] = (f32x4){0.f, 0.f, 0.f, 0.f};
    const ushort* WT = WsT + e * Gx * Fx;   // [g][f]
    unsigned int aswz = ((unsigned int)(row & 7)) << 4;
    #pragma unroll
    for (int ks = 0; ks < 4; ++ks) {
        unsigned int abyte = ((unsigned int)(row * 256 + ks * 64 + kg * 16)) ^ aswz;
        bf16x8 af = *(const bf16x8*)((const char*)sXb + abyte);
        #pragma unroll
        for (int jt = 0; jt < 4; ++jt) {
            bf16x8 bf = *(const bf16x8*)&WT[(size_t)(jt * 16 + arow) * Fx + ks * 32 + kg * 8];
            acc[jt] = __builtin_amdgcn_mfma_f32_16x16x32_bf16(af, bf, acc[jt], 0, 0, 0);
        }
    }
    float a1v[4], a2v[4];
    #pragma unroll
    for (int jt = 0; jt < 4; ++jt) {
        a1v[jt] = a[e * 2 * Gx + jt * 16 + arow];
        a2v[jt] = a[e * 2 * Gx + Gx + jt * 16 + arow];
    }
    int m0 = n0 + wave * 16 + kg * 4;
    #pragma unroll
    for (int jt = 0; jt < 4; ++jt) {
        int g = jt * 16 + arow;
        ushort4 v;
        v.x = f2bf(acc[jt][0]); v.y = f2bf(acc[jt][1]);
        v.z = f2bf(acc[jt][2]); v.w = f2bf(acc[jt][3]);
        *(ushort4*)&Whb[((size_t)be * Gx + g) * Nx + m0] = v;
    }
    #pragma unroll
    for (int reg = 0; reg < 4; ++reg) {
        float p1 = acc[0][reg] * a1v[0] + acc[1][reg] * a1v[1] + acc[2][reg] * a1v[2] + acc[3][reg] * a1v[3];
        float p2 = acc[0][reg] * a2v[0] + acc[1][reg] * a2v[1] + acc[2][reg] * a2v[2] + acc[3][reg] * a2v[3];
        #pragma unroll
        for (int off = 1; off < 16; off <<= 1) {
            p1 += __shfl_xor(p1, off, 64);
            p2 += __shfl_xor(p2, off, 64);
        }
        if (arow == 0) {
            w1[be * Nx + m0 + reg] = p1;
            w2[be * Nx + m0 + reg] = p2;
        }
    }
}

// ---- K2: 64-row tiles; binned edges -> owner-compacted softmax -> MFMA PV --
__global__ __launch_bounds__(512) void k2_att(const ushort* __restrict__ binned,
                                              const int* __restrict__ offs,
                                              const ushort* __restrict__ Whb,
                                              const float* __restrict__ w1g,
                                              const float* __restrict__ w2g,
                                              ushort* __restrict__ Hb) {
    __shared__ ushort P[64 * 512];          // 64KB; first 33.8KB doubles as cnt
    __shared__ float sw2[512];              // pre-scaled by log2e
    __shared__ float sw1[64];
    __shared__ float sinv[64];
    __shared__ float rowsum[64];
    __shared__ int   rowK[64];
    __shared__ ushort olist[4096];          // compacted distinct (r<<9|d)
    __shared__ int ocnt;
    unsigned int* cnt = (unsigned int*)P;   // [64][132]
    int be = blockIdx.x; int b = be >> 2; int e = be & 3;
    int tile = blockIdx.y; int n0 = tile * 64;
    int tid = threadIdx.x;
    for (int i = tid; i < 64 * 132; i += 512) cnt[i] = 0u;
    sw2[tid] = w2g[be * Nx + tid] * L2E;
    if (tid < 64) {
        sw1[tid] = w1g[be * Nx + n0 + tid] * L2E;
        rowsum[tid] = 0.f; rowK[tid] = 0;
    }
    if (tid == 0) ocnt = 0;
    __syncthreads();
    // phase 2: scatter binned edges into byte counters; old-byte==0 => owner
    int t0 = offs[be * 9 + tile], t1 = offs[be * 9 + tile + 1];
    const ushort* bin = binned + (size_t)be * NEDGE;
    for (int i = t0 + tid; i < t1; i += 512) {
        unsigned int pk = bin[i];
        unsigned int sh = (pk & 3u) * 8;
        unsigned int old = atomicAdd(&cnt[(pk >> 9) * 132 + ((pk & 511u) >> 2)], 1u << sh);
        if (((old >> sh) & 255u) == 0u) {
            int ix = atomicAdd(&ocnt, 1);
            if (ix < 4096) olist[ix] = (ushort)pk;
        }
    }
    __syncthreads();
    // phase 3a: process owned entries (<=8/thread, static regs)
    int tot = ocnt; if (tot > 4096) tot = 4096;
    const unsigned char* cb = (const unsigned char*)cnt;
    ushort pbv[8]; int pkv[8];
    #pragma unroll
    for (int u = 0; u < 8; ++u) {
        int i = tid + u * 512;
        bool v = i < tot;
        int pk = v ? (int)olist[i] : 0;
        int r = pk >> 9, d = pk & 511;
        float c = (float)cb[r * 528 + d];
        float ew = __builtin_exp2f(fminf((sw1[r] + sw2[d]) * c, 120.f));
        if (v) {
            atomicAdd(&rowsum[r], ew);
            atomicAdd(&rowK[r], 1);
        }
        pbv[u] = f2bf(ew * c);
        pkv[u] = v ? pk : -1;
    }
    __syncthreads();   // cnt fully consumed; P may be overwritten
    // phase 3b: zero P (128B per thread)
    {
        uint4 z = {0u, 0u, 0u, 0u};
        #pragma unroll
        for (int u = 0; u < 8; ++u)
            *(uint4*)((char*)P + tid * 128 + u * 16) = z;
    }
    __syncthreads();
    // phase 3c: scatter bf16 weights (unique (r,d) -> race-free); sinv
    #pragma unroll
    for (int u = 0; u < 8; ++u) {
        if (pkv[u] >= 0) {
            int r = pkv[u] >> 9, d = pkv[u] & 511;
            unsigned int byteo = ((unsigned int)(r * 1024 + d * 2)) ^ (((unsigned int)(r & 7)) << 4);
            *(ushort*)((char*)P + byteo) = pbv[u];
        }
    }
    if (tid < 64) sinv[tid] = 1.f / (rowsum[tid] + (float)(Nx - rowK[tid]));
    __syncthreads();
    // phase 4: H-tile = P @ Whb; 8 waves x 2 sub-tiles (B fragments reused)
    int wave = tid >> 6, lane = tid & 63;
    int wr2 = wave >> 2, wc = wave & 3;
    int rowa = wr2 * 32 + (lane & 15);
    int rowb = rowa + 16;
    int kgrp = lane >> 4;
    f32x4 acca = {0.f, 0.f, 0.f, 0.f};
    f32x4 accb = {0.f, 0.f, 0.f, 0.f};
    const ushort* WB = Whb + (size_t)be * Gx * Nx;
    int g0 = wc * 16 + (lane & 15);
    const ushort* Bp = WB + (size_t)g0 * Nx + kgrp * 8;
    unsigned int aswza = ((unsigned int)(rowa & 7)) << 4;
    __builtin_amdgcn_s_setprio(1);
    #pragma unroll
    for (int ks = 0; ks < 16; ++ks) {
        bf16x8 bfv = *(const bf16x8*)(Bp + ks * 32);
        unsigned int ka = (unsigned int)(ks * 64 + kgrp * 16);
        unsigned int offa = ((unsigned int)(rowa * 1024) + ka) ^ aswza;
        unsigned int offb = ((unsigned int)(rowb * 1024) + ka) ^ aswza;
        bf16x8 afa = *(const bf16x8*)((const char*)P + offa);
        bf16x8 afb = *(const bf16x8*)((const char*)P + offb);
        acca = __builtin_amdgcn_mfma_f32_16x16x32_bf16(afa, bfv, acca, 0, 0, 0);
        accb = __builtin_amdgcn_mfma_f32_16x16x32_bf16(afb, bfv, accb, 0, 0, 0);
    }
    __builtin_amdgcn_s_setprio(0);
    #pragma unroll
    for (int reg = 0; reg < 4; ++reg) {
        int ra = n0 + wr2 * 32 + kgrp * 4 + reg;
        float iva = sinv[wr2 * 32 + kgrp * 4 + reg];
        float ivb = sinv[wr2 * 32 + 16 + kgrp * 4 + reg];
        Hb[((size_t)(b * Nx) + ra) * (Ex * Gx) + e * Gx + wc * 16 + (lane & 15)] =
            f2bf(acca[reg] * iva);
        Hb[((size_t)(b * Nx) + ra + 16) * (Ex * Gx) + e * Gx + wc * 16 + (lane & 15)] =
            f2bf(accb[reg] * ivb);
    }
}

// ---- K3: h_pre = bf16(Hb @ W0 + b) via MFMA; fp32 BN partials --------------
__global__ __launch_bounds__(256) void k3_lin0(const ushort* __restrict__ Hb,
                                               const ushort* __restrict__ W0T,
                                               const float* __restrict__ lin0_b,
                                               ushort* __restrict__ h_pre,
                                               float* __restrict__ partials) {
    __shared__ float red_s[2][256], red_q[2][256];
    int tid = threadIdx.x, wave = tid >> 6, lane = tid & 63;
    int wr = wave >> 1, wc = wave & 1;
    int row0 = blockIdx.x * 32 + wr * 16;
    int arow = lane & 15, kg = lane >> 4;
    const ushort* A = Hb + (size_t)(row0 + arow) * HIDx;
    f32x4 acc[8];
    #pragma unroll
    for (int t = 0; t < 8; ++t) acc[t] = (f32x4){0.f, 0.f, 0.f, 0.f};
    #pragma unroll
    for (int ks = 0; ks < 8; ++ks) {
        int k0 = ks * 32 + kg * 8;
        bf16x8 af = *(const bf16x8*)&A[k0];
        #pragma unroll
        for (int jt = 0; jt < 8; ++jt) {
            bf16x8 bf = *(const bf16x8*)&W0T[(size_t)(wc * 128 + jt * 16 + arow) * HIDx + k0];
            acc[jt] = __builtin_amdgcn_mfma_f32_16x16x32_bf16(af, bf, acc[jt], 0, 0, 0);
        }
    }
    #pragma unroll
    for (int jt = 0; jt < 8; ++jt) {
        int col = wc * 128 + jt * 16 + arow;
        float b = lin0_b[col];
        float s = 0.f, q = 0.f;
        #pragma unroll
        for (int reg = 0; reg < 4; ++reg) {
            float v = acc[jt][reg] + b;
            h_pre[(size_t)(row0 + kg * 4 + reg) * HIDx + col] = f2bf(v);
            s += v; q += v * v;
        }
        s += __shfl_xor(s, 16, 64); s += __shfl_xor(s, 32, 64);
        q += __shfl_xor(q, 16, 64); q += __shfl_xor(q, 32, 64);
        if (lane < 16) { red_s[wr][col] = s; red_q[wr][col] = q; }
    }
    __syncthreads();
    int j = tid;
    partials[(size_t)blockIdx.x * 2 * HIDx + j] = red_s[0][j] + red_s[1][j];
    partials[(size_t)blockIdx.x * 2 * HIDx + HIDx + j] = red_q[0][j] + red_q[1][j];
}

// ---- K3b: finalize BN stats -> scale/bias ----------------------------------
__global__ __launch_bounds__(256) void k3b_stats(const float* __restrict__ partials,
                                                 const float* __restrict__ gamma,
                                                 const float* __restrict__ beta,
                                                 float* __restrict__ sb) {
    __shared__ float rs[8][32], rq[8][32];
    int jl = threadIdx.x & 31, sl = threadIdx.x >> 5;
    int j = blockIdx.x * 32 + jl;
    float s = 0.f, q = 0.f;
    for (int blk = sl; blk < 512; blk += 8) {
        s += partials[blk * 512 + j];
        q += partials[blk * 512 + 256 + j];
    }
    rs[sl][jl] = s; rq[sl][jl] = q;
    __syncthreads();
    if (threadIdx.x < 32) {
        float S = 0.f, Q = 0.f;
        #pragma unroll
        for (int t = 0; t < 8; ++t) { S += rs[t][jl]; Q += rq[t][jl]; }
        const float invM = 1.f / 16384.f;
        float mu = S * invM;
        float var = fmaxf(Q * invM - mu * mu, 0.f);
        float sc = gamma[j] * rsqrtf(var + 1e-5f);
        sb[j] = sc;
        sb[256 + j] = beta[j] - mu * sc;
    }
}

// ---- K4: out = elu(bn(h_pre)) @ W1 + b via MFMA ----------------------------
__global__ __launch_bounds__(256) void k4_lin1(const ushort* __restrict__ h_pre,
                                               const float* __restrict__ sb,
                                               const ushort* __restrict__ W1T,
                                               const float* __restrict__ lin1_b,
                                               float* __restrict__ out) {
    int tid = threadIdx.x, wave = tid >> 6, lane = tid & 63;
    int wr = wave >> 1, wc = wave & 1;
    int row0 = blockIdx.x * 32 + wr * 16;
    int arow = lane & 15, kg = lane >> 4;
    const ushort* A = h_pre + (size_t)(row0 + arow) * HIDx;
    f32x4 acc[4];
    #pragma unroll
    for (int t = 0; t < 4; ++t) acc[t] = (f32x4){0.f, 0.f, 0.f, 0.f};
    #pragma unroll
    for (int ks = 0; ks < 8; ++ks) {
        int k0 = ks * 32 + kg * 8;
        bf16x8 hv = *(const bf16x8*)&A[k0];
        float4 sc0 = *(const float4*)&sb[k0];
        float4 sc1 = *(const float4*)&sb[k0 + 4];
        float4 bi0 = *(const float4*)&sb[256 + k0];
        float4 bi1 = *(const float4*)&sb[256 + k0 + 4];
        float scv[8] = {sc0.x, sc0.y, sc0.z, sc0.w, sc1.x, sc1.y, sc1.z, sc1.w};
        float biv[8] = {bi0.x, bi0.y, bi0.z, bi0.w, bi1.x, bi1.y, bi1.z, bi1.w};
        bf16x8 af;
        #pragma unroll
        for (int u = 0; u < 8; ++u) {
            float v = bf2f((ushort)hv[u]) * scv[u] + biv[u];
            v = v > 0.f ? v : expm1f(v);
            af[u] = (short)f2bf(v);
        }
        #pragma unroll
        for (int jt = 0; jt < 4; ++jt) {
            bf16x8 bf = *(const bf16x8*)&W1T[(size_t)(wc * 64 + jt * 16 + arow) * HIDx + k0];
            acc[jt] = __builtin_amdgcn_mfma_f32_16x16x32_bf16(af, bf, acc[jt], 0, 0, 0);
        }
    }
    #pragma unroll
    for (int jt = 0; jt < 4; ++jt) {
        int col = wc * 64 + jt * 16 + arow;
        float b = lin1_b[col];
        #pragma unroll
        for (int reg = 0; reg < 4; ++reg)
            out[(size_t)(row0 + kg * 4 + reg) * EMBx + col] = acc[jt][reg] + b;
    }
}

extern "C" void kernel_launch(void* const* d_in, const int* in_sizes, int n_in,
                              void* d_out, int out_size, void* d_ws, size_t ws_size,
                              hipStream_t stream) {
    const float* X      = (const float*)d_in[0];
    const int*   edges  = (const int*)d_in[1];
    const float* Ws     = (const float*)d_in[2];
    const float* a      = (const float*)d_in[3];
    const float* lin0_w = (const float*)d_in[4];
    const float* lin0_b = (const float*)d_in[5];
    const float* gamma  = (const float*)d_in[6];
    const float* beta   = (const float*)d_in[7];
    const float* lin1_w = (const float*)d_in[8];
    const float* lin1_b = (const float*)d_in[9];
    float* ws = (float*)d_ws;

    ushort* Whb     = (ushort*)ws;
    ushort* h_pre   = (ushort*)ws;
    ushort* binned  = (ushort*)ws + 4194304;
    int*    offs    = (int*)(ws + 2621440);
    ushort* Hb      = (ushort*)(ws + 4194304);
    float*  w1      = ws + 8388608;              // 65,536
    float*  w2      = ws + 8454144;              // 65,536
    float*  partials= ws + 8519680;              // 262,144
    float*  sb      = ws + 8781824;              // 512
    ushort* WsT     = (ushort*)(ws + 8782336);   // 32,768 ushorts
    ushort* W0T     = (ushort*)(ws + 8798720);   // 65,536 ushorts
    ushort* W1T     = (ushort*)(ws + 8831488);   // 32,768 ushorts
    float*  out     = (float*)d_out;

    k0b    <<<dim3(384), 512, 0, stream>>>(edges, lin0_w, lin1_w, Ws, W0T, W1T, WsT, binned, offs);
    k1_wh  <<<dim3(1024), 256, 0, stream>>>(X, WsT, a, Whb, w1, w2);
    k2_att <<<dim3(Bx * Ex, Nx / 64), 512, 0, stream>>>(binned, offs, Whb, w1, w2, Hb);
    k3_lin0<<<dim3(512), 256, 0, stream>>>(Hb, W0T, lin0_b, h_pre, partials);
    k3b_stats<<<8, 256, 0, stream>>>(partials, gamma, beta, sb);
    k4_lin1<<<dim3(512), 256, 0, stream>>>(h_pre, sb, W1T, lin1_b, out);
}

// Round 19
// 120.889 us; speedup vs baseline: 1.0520x; 1.0029x over previous
//
#include <hip/hip_runtime.h>

#define Bx 32
#define Nx 512
#define Ex 4
#define Fx 128
#define Gx 64
#define HIDx 256
#define EMBx 128
#define NEDGE 8192

typedef __attribute__((ext_vector_type(8))) short bf16x8;
typedef __attribute__((ext_vector_type(4))) float f32x4;

#define L2E 1.44269504f

__device__ __forceinline__ ushort f2bf(float x) {
    unsigned int u = __float_as_uint(x);
    u += 0x7fffu + ((u >> 16) & 1u);
    return (ushort)(u >> 16);
}
__device__ __forceinline__ float bf2f(ushort h) {
    return __uint_as_float(((unsigned int)h) << 16);
}

// ---- K0b: edge binning into 8 x 64-row segments + weight transpose/cast ----
// binned output staged in LDS, then written coalesced (was: random 2B stores)
__global__ __launch_bounds__(512) void k0b(const int* __restrict__ edges,
                                           const float* __restrict__ w0,
                                           const float* __restrict__ w1f,
                                           const float* __restrict__ Wsf,
                                           ushort* __restrict__ W0T,
                                           ushort* __restrict__ W1T,
                                           ushort* __restrict__ WsT,
                                           ushort* __restrict__ binned,
                                           int* __restrict__ offs) {
    __shared__ int hist8[8][8];
    __shared__ int offl[9];
    __shared__ int cur[8];
    __shared__ ushort sbin[NEDGE];          // 16KB staging for coalesced out
    int blk = blockIdx.x, tid = threadIdx.x;
    if (blk < 128) {
        int wave = tid >> 6;
        if (tid < 64) ((int*)hist8)[tid] = 0;
        __syncthreads();
        const int4* s4p = (const int4*)(edges + (size_t)blk * 2 * NEDGE);
        const int4* d4p = (const int4*)(edges + (size_t)blk * 2 * NEDGE + NEDGE);
        for (int i = tid; i < NEDGE / 4; i += 512) {
            int4 s4 = s4p[i];
            atomicAdd(&hist8[wave][s4.x >> 6], 1);
            atomicAdd(&hist8[wave][s4.y >> 6], 1);
            atomicAdd(&hist8[wave][s4.z >> 6], 1);
            atomicAdd(&hist8[wave][s4.w >> 6], 1);
        }
        __syncthreads();
        if (tid == 0) {
            int run = 0;
            for (int t = 0; t < 8; ++t) {
                offl[t] = run;
                int s = 0;
                #pragma unroll
                for (int w = 0; w < 8; ++w) s += hist8[w][t];
                run += s;
            }
            offl[8] = run;
            for (int t = 0; t <= 8; ++t) offs[blk * 9 + t] = offl[t];
        }
        __syncthreads();
        if (tid < 8) cur[tid] = offl[tid];
        __syncthreads();
        for (int i = tid; i < NEDGE / 4; i += 512) {
            int4 s4 = s4p[i]; int4 d4 = d4p[i];
            int ss[4] = {s4.x, s4.y, s4.z, s4.w};
            int dd[4] = {d4.x, d4.y, d4.z, d4.w};
            #pragma unroll
            for (int u = 0; u < 4; ++u) {
                int t = ss[u] >> 6;
                int pos = atomicAdd(&cur[t], 1);
                sbin[pos] = (ushort)(((ss[u] & 63) << 9) | dd[u]);
            }
        }
        __syncthreads();
        ushort* bout = binned + (size_t)blk * NEDGE;
        const uint4* sb4 = (const uint4*)sbin;
        uint4* bo4 = (uint4*)bout;
        for (int i = tid; i < NEDGE / 8; i += 512) bo4[i] = sb4[i];
    } else if (blk < 256) {
        int idx = (blk - 128) * 512 + tid;
        int j = idx >> 8, k = idx & 255;
        W0T[j * HIDx + k] = f2bf(w0[k * HIDx + j]);
    } else if (blk < 320) {
        int idx = (blk - 256) * 512 + tid;
        int j = idx >> 8, k = idx & 255;
        W1T[j * HIDx + k] = f2bf(w1f[k * EMBx + j]);
    } else {
        int idx = (blk - 320) * 512 + tid;
        int eg = idx >> 7, f = idx & 127;
        WsT[eg * Fx + f] = f2bf(Wsf[((eg >> 6) * Fx + f) * Gx + (eg & 63)]);
    }
}

// ---- K1: Whb[be,g,m] = bf16(X @ Ws) via MFMA; w1/w2 = Wh . a ---------------
__global__ __launch_bounds__(256) void k1_wh(const float* __restrict__ X,
                                             const ushort* __restrict__ WsT,
                                             const float* __restrict__ a,
                                             ushort* __restrict__ Whb,
                                             float* __restrict__ w1,
                                             float* __restrict__ w2) {
    __shared__ ushort sXb[64 * 128];   // 16KB, XOR-swizzled bf16 A tile
    int id = blockIdx.x;
    int e = id & 3;
    int rest = id >> 2;
    int tile = rest & 7;
    int b = rest >> 3;
    int be = b * 4 + e;
    int n0 = tile * 64;
    int tid = threadIdx.x;
    for (int i = tid; i < 2048; i += 256) {
        int row = i >> 5, kq = i & 31;
        float4 xv = *(const float4*)&X[(size_t)(b * Nx + n0 + row) * Fx + kq * 4];
        ushort4 hv;
        hv.x = f2bf(xv.x); hv.y = f2bf(xv.y); hv.z = f2bf(xv.z); hv.w = f2bf(xv.w);
        unsigned int byteo = ((unsigned int)(row * 256 + kq * 8)) ^ (((unsigned int)(row & 7)) << 4);
        *(ushort4*)((char*)sXb + byteo) = hv;
    }
    __syncthreads();
    int wave = tid >> 6, lane = tid & 63;
    int arow = lane & 15, kg = lane >> 4;
    int row = wave * 16 + arow;
    f32x4 acc[4];
    #pragma unroll
    for (int t = 0; t < 4; ++t) acc[t] = (f32x4){0.f, 0.f, 0.f, 0.f};
    const ushort* WT = WsT + e * Gx * Fx;   // [g][f]
    unsigned int aswz = ((unsigned int)(row & 7)) << 4;
    #pragma unroll
    for (int ks = 0; ks < 4; ++ks) {
        unsigned int abyte = ((unsigned int)(row * 256 + ks * 64 + kg * 16)) ^ aswz;
        bf16x8 af = *(const bf16x8*)((const char*)sXb + abyte);
        #pragma unroll
        for (int jt = 0; jt < 4; ++jt) {
            bf16x8 bf = *(const bf16x8*)&WT[(size_t)(jt * 16 + arow) * Fx + ks * 32 + kg * 8];
            acc[jt] = __builtin_amdgcn_mfma_f32_16x16x32_bf16(af, bf, acc[jt], 0, 0, 0);
        }
    }
    float a1v[4], a2v[4];
    #pragma unroll
    for (int jt = 0; jt < 4; ++jt) {
        a1v[jt] = a[e * 2 * Gx + jt * 16 + arow];
        a2v[jt] = a[e * 2 * Gx + Gx + jt * 16 + arow];
    }
    int m0 = n0 + wave * 16 + kg * 4;
    #pragma unroll
    for (int jt = 0; jt < 4; ++jt) {
        int g = jt * 16 + arow;
        ushort4 v;
        v.x = f2bf(acc[jt][0]); v.y = f2bf(acc[jt][1]);
        v.z = f2bf(acc[jt][2]); v.w = f2bf(acc[jt][3]);
        *(ushort4*)&Whb[((size_t)be * Gx + g) * Nx + m0] = v;
    }
    #pragma unroll
    for (int reg = 0; reg < 4; ++reg) {
        float p1 = acc[0][reg] * a1v[0] + acc[1][reg] * a1v[1] + acc[2][reg] * a1v[2] + acc[3][reg] * a1v[3];
        float p2 = acc[0][reg] * a2v[0] + acc[1][reg] * a2v[1] + acc[2][reg] * a2v[2] + acc[3][reg] * a2v[3];
        #pragma unroll
        for (int off = 1; off < 16; off <<= 1) {
            p1 += __shfl_xor(p1, off, 64);
            p2 += __shfl_xor(p2, off, 64);
        }
        if (arow == 0) {
            w1[be * Nx + m0 + reg] = p1;
            w2[be * Nx + m0 + reg] = p2;
        }
    }
}

// ---- K2: 64-row tiles; binned edges -> owner-compacted softmax -> MFMA PV --
__global__ __launch_bounds__(512) void k2_att(const ushort* __restrict__ binned,
                                              const int* __restrict__ offs,
                                              const ushort* __restrict__ Whb,
                                              const float* __restrict__ w1g,
                                              const float* __restrict__ w2g,
                                              ushort* __restrict__ Hb) {
    __shared__ ushort P[64 * 512];          // 64KB; first 33.8KB doubles as cnt
    __shared__ float sw2[512];              // pre-scaled by log2e
    __shared__ float sw1[64];
    __shared__ float sinv[64];
    __shared__ float rowsum[64];
    __shared__ int   rowK[64];
    __shared__ ushort olist[4096];          // compacted distinct (r<<9|d)
    __shared__ int ocnt;
    unsigned int* cnt = (unsigned int*)P;   // [64][132]
    int be = blockIdx.x; int b = be >> 2; int e = be & 3;
    int tile = blockIdx.y; int n0 = tile * 64;
    int tid = threadIdx.x;
    for (int i = tid; i < 64 * 132; i += 512) cnt[i] = 0u;
    sw2[tid] = w2g[be * Nx + tid] * L2E;
    if (tid < 64) {
        sw1[tid] = w1g[be * Nx + n0 + tid] * L2E;
        rowsum[tid] = 0.f; rowK[tid] = 0;
    }
    if (tid == 0) ocnt = 0;
    __syncthreads();
    // phase 2: scatter binned edges into byte counters; old-byte==0 => owner
    int t0 = offs[be * 9 + tile], t1 = offs[be * 9 + tile + 1];
    const ushort* bin = binned + (size_t)be * NEDGE;
    for (int i = t0 + tid; i < t1; i += 512) {
        unsigned int pk = bin[i];
        unsigned int sh = (pk & 3u) * 8;
        unsigned int old = atomicAdd(&cnt[(pk >> 9) * 132 + ((pk & 511u) >> 2)], 1u << sh);
        if (((old >> sh) & 255u) == 0u) {
            int ix = atomicAdd(&ocnt, 1);
            if (ix < 4096) olist[ix] = (ushort)pk;
        }
    }
    __syncthreads();
    // phase 3a: process owned entries (<=8/thread, static regs)
    int tot = ocnt; if (tot > 4096) tot = 4096;
    const unsigned char* cb = (const unsigned char*)cnt;
    ushort pbv[8]; int pkv[8];
    #pragma unroll
    for (int u = 0; u < 8; ++u) {
        int i = tid + u * 512;
        bool v = i < tot;
        int pk = v ? (int)olist[i] : 0;
        int r = pk >> 9, d = pk & 511;
        float c = (float)cb[r * 528 + d];
        float ew = __builtin_exp2f(fminf((sw1[r] + sw2[d]) * c, 120.f));
        if (v) {
            atomicAdd(&rowsum[r], ew);
            atomicAdd(&rowK[r], 1);
        }
        pbv[u] = f2bf(ew * c);
        pkv[u] = v ? pk : -1;
    }
    __syncthreads();   // cnt fully consumed; P may be overwritten
    // phase 3b: zero P (128B per thread)
    {
        uint4 z = {0u, 0u, 0u, 0u};
        #pragma unroll
        for (int u = 0; u < 8; ++u)
            *(uint4*)((char*)P + tid * 128 + u * 16) = z;
    }
    __syncthreads();
    // phase 3c: scatter bf16 weights (unique (r,d) -> race-free); sinv
    #pragma unroll
    for (int u = 0; u < 8; ++u) {
        if (pkv[u] >= 0) {
            int r = pkv[u] >> 9, d = pkv[u] & 511;
            unsigned int byteo = ((unsigned int)(r * 1024 + d * 2)) ^ (((unsigned int)(r & 7)) << 4);
            *(ushort*)((char*)P + byteo) = pbv[u];
        }
    }
    if (tid < 64) sinv[tid] = 1.f / (rowsum[tid] + (float)(Nx - rowK[tid]));
    __syncthreads();
    // phase 4: H-tile = P @ Whb; 8 waves x 2 sub-tiles (B fragments reused)
    int wave = tid >> 6, lane = tid & 63;
    int wr2 = wave >> 2, wc = wave & 3;
    int rowa = wr2 * 32 + (lane & 15);
    int rowb = rowa + 16;
    int kgrp = lane >> 4;
    f32x4 acca = {0.f, 0.f, 0.f, 0.f};
    f32x4 accb = {0.f, 0.f, 0.f, 0.f};
    const ushort* WB = Whb + (size_t)be * Gx * Nx;
    int g0 = wc * 16 + (lane & 15);
    const ushort* Bp = WB + (size_t)g0 * Nx + kgrp * 8;
    unsigned int aswza = ((unsigned int)(rowa & 7)) << 4;
    __builtin_amdgcn_s_setprio(1);
    #pragma unroll
    for (int ks = 0; ks < 16; ++ks) {
        bf16x8 bfv = *(const bf16x8*)(Bp + ks * 32);
        unsigned int ka = (unsigned int)(ks * 64 + kgrp * 16);
        unsigned int offa = ((unsigned int)(rowa * 1024) + ka) ^ aswza;
        unsigned int offb = ((unsigned int)(rowb * 1024) + ka) ^ aswza;
        bf16x8 afa = *(const bf16x8*)((const char*)P + offa);
        bf16x8 afb = *(const bf16x8*)((const char*)P + offb);
        acca = __builtin_amdgcn_mfma_f32_16x16x32_bf16(afa, bfv, acca, 0, 0, 0);
        accb = __builtin_amdgcn_mfma_f32_16x16x32_bf16(afb, bfv, accb, 0, 0, 0);
    }
    __builtin_amdgcn_s_setprio(0);
    #pragma unroll
    for (int reg = 0; reg < 4; ++reg) {
        int ra = n0 + wr2 * 32 + kgrp * 4 + reg;
        float iva = sinv[wr2 * 32 + kgrp * 4 + reg];
        float ivb = sinv[wr2 * 32 + 16 + kgrp * 4 + reg];
        Hb[((size_t)(b * Nx) + ra) * (Ex * Gx) + e * Gx + wc * 16 + (lane & 15)] =
            f2bf(acca[reg] * iva);
        Hb[((size_t)(b * Nx) + ra + 16) * (Ex * Gx) + e * Gx + wc * 16 + (lane & 15)] =
            f2bf(accb[reg] * ivb);
    }
}

// ---- K3: h_pre = bf16(Hb @ W0 + b) via MFMA; fp32 BN partials --------------
__global__ __launch_bounds__(256) void k3_lin0(const ushort* __restrict__ Hb,
                                               const ushort* __restrict__ W0T,
                                               const float* __restrict__ lin0_b,
                                               ushort* __restrict__ h_pre,
                                               float* __restrict__ partials) {
    __shared__ float red_s[2][256], red_q[2][256];
    int tid = threadIdx.x, wave = tid >> 6, lane = tid & 63;
    int wr = wave >> 1, wc = wave & 1;
    int row0 = blockIdx.x * 32 + wr * 16;
    int arow = lane & 15, kg = lane >> 4;
    const ushort* A = Hb + (size_t)(row0 + arow) * HIDx;
    f32x4 acc[8];
    #pragma unroll
    for (int t = 0; t < 8; ++t) acc[t] = (f32x4){0.f, 0.f, 0.f, 0.f};
    #pragma unroll
    for (int ks = 0; ks < 8; ++ks) {
        int k0 = ks * 32 + kg * 8;
        bf16x8 af = *(const bf16x8*)&A[k0];
        #pragma unroll
        for (int jt = 0; jt < 8; ++jt) {
            bf16x8 bf = *(const bf16x8*)&W0T[(size_t)(wc * 128 + jt * 16 + arow) * HIDx + k0];
            acc[jt] = __builtin_amdgcn_mfma_f32_16x16x32_bf16(af, bf, acc[jt], 0, 0, 0);
        }
    }
    #pragma unroll
    for (int jt = 0; jt < 8; ++jt) {
        int col = wc * 128 + jt * 16 + arow;
        float b = lin0_b[col];
        float s = 0.f, q = 0.f;
        #pragma unroll
        for (int reg = 0; reg < 4; ++reg) {
            float v = acc[jt][reg] + b;
            h_pre[(size_t)(row0 + kg * 4 + reg) * HIDx + col] = f2bf(v);
            s += v; q += v * v;
        }
        s += __shfl_xor(s, 16, 64); s += __shfl_xor(s, 32, 64);
        q += __shfl_xor(q, 16, 64); q += __shfl_xor(q, 32, 64);
        if (lane < 16) { red_s[wr][col] = s; red_q[wr][col] = q; }
    }
    __syncthreads();
    int j = tid;
    partials[(size_t)blockIdx.x * 2 * HIDx + j] = red_s[0][j] + red_s[1][j];
    partials[(size_t)blockIdx.x * 2 * HIDx + HIDx + j] = red_q[0][j] + red_q[1][j];
}

// ---- K3b: finalize BN stats -> scale/bias ----------------------------------
__global__ __launch_bounds__(256) void k3b_stats(const float* __restrict__ partials,
                                                 const float* __restrict__ gamma,
                                                 const float* __restrict__ beta,
                                                 float* __restrict__ sb) {
    __shared__ float rs[8][32], rq[8][32];
    int jl = threadIdx.x & 31, sl = threadIdx.x >> 5;
    int j = blockIdx.x * 32 + jl;
    float s = 0.f, q = 0.f;
    for (int blk = sl; blk < 512; blk += 8) {
        s += partials[blk * 512 + j];
        q += partials[blk * 512 + 256 + j];
    }
    rs[sl][jl] = s; rq[sl][jl] = q;
    __syncthreads();
    if (threadIdx.x < 32) {
        float S = 0.f, Q = 0.f;
        #pragma unroll
        for (int t = 0; t < 8; ++t) { S += rs[t][jl]; Q += rq[t][jl]; }
        const float invM = 1.f / 16384.f;
        float mu = S * invM;
        float var = fmaxf(Q * invM - mu * mu, 0.f);
        float sc = gamma[j] * rsqrtf(var + 1e-5f);
        sb[j] = sc;
        sb[256 + j] = beta[j] - mu * sc;
    }
}

// ---- K4: out = elu(bn(h_pre)) @ W1 + b via MFMA ----------------------------
__global__ __launch_bounds__(256) void k4_lin1(const ushort* __restrict__ h_pre,
                                               const float* __restrict__ sb,
                                               const ushort* __restrict__ W1T,
                                               const float* __restrict__ lin1_b,
                                               float* __restrict__ out) {
    int tid = threadIdx.x, wave = tid >> 6, lane = tid & 63;
    int wr = wave >> 1, wc = wave & 1;
    int row0 = blockIdx.x * 32 + wr * 16;
    int arow = lane & 15, kg = lane >> 4;
    const ushort* A = h_pre + (size_t)(row0 + arow) * HIDx;
    f32x4 acc[4];
    #pragma unroll
    for (int t = 0; t < 4; ++t) acc[t] = (f32x4){0.f, 0.f, 0.f, 0.f};
    #pragma unroll
    for (int ks = 0; ks < 8; ++ks) {
        int k0 = ks * 32 + kg * 8;
        bf16x8 hv = *(const bf16x8*)&A[k0];
        float4 sc0 = *(const float4*)&sb[k0];
        float4 sc1 = *(const float4*)&sb[k0 + 4];
        float4 bi0 = *(const float4*)&sb[256 + k0];
        float4 bi1 = *(const float4*)&sb[256 + k0 + 4];
        float scv[8] = {sc0.x, sc0.y, sc0.z, sc0.w, sc1.x, sc1.y, sc1.z, sc1.w};
        float biv[8] = {bi0.x, bi0.y, bi0.z, bi0.w, bi1.x, bi1.y, bi1.z, bi1.w};
        bf16x8 af;
        #pragma unroll
        for (int u = 0; u < 8; ++u) {
            float v = bf2f((ushort)hv[u]) * scv[u] + biv[u];
            v = v > 0.f ? v : expm1f(v);
            af[u] = (short)f2bf(v);
        }
        #pragma unroll
        for (int jt = 0; jt < 4; ++jt) {
            bf16x8 bf = *(const bf16x8*)&W1T[(size_t)(wc * 64 + jt * 16 + arow) * HIDx + k0];
            acc[jt] = __builtin_amdgcn_mfma_f32_16x16x32_bf16(af, bf, acc[jt], 0, 0, 0);
        }
    }
    #pragma unroll
    for (int jt = 0; jt < 4; ++jt) {
        int col = wc * 64 + jt * 16 + arow;
        float b = lin1_b[col];
        #pragma unroll
        for (int reg = 0; reg < 4; ++reg)
            out[(size_t)(row0 + kg * 4 + reg) * EMBx + col] = acc[jt][reg] + b;
    }
}

extern "C" void kernel_launch(void* const* d_in, const int* in_sizes, int n_in,
                              void* d_out, int out_size, void* d_ws, size_t ws_size,
                              hipStream_t stream) {
    const float* X      = (const float*)d_in[0];
    const int*   edges  = (const int*)d_in[1];
    const float* Ws     = (const float*)d_in[2];
    const float* a      = (const float*)d_in[3];
    const float* lin0_w = (const float*)d_in[4];
    const float* lin0_b = (const float*)d_in[5];
    const float* gamma  = (const float*)d_in[6];
    const float* beta   = (const float*)d_in[7];
    const float* lin1_w = (const float*)d_in[8];
    const float* lin1_b = (const float*)d_in[9];
    float* ws = (float*)d_ws;

    ushort* Whb     = (ushort*)ws;
    ushort* h_pre   = (ushort*)ws;
    ushort* binned  = (ushort*)ws + 4194304;
    int*    offs    = (int*)(ws + 2621440);
    ushort* Hb      = (ushort*)(ws + 4194304);
    float*  w1      = ws + 8388608;              // 65,536
    float*  w2      = ws + 8454144;              // 65,536
    float*  partials= ws + 8519680;              // 262,144
    float*  sb      = ws + 8781824;              // 512
    ushort* WsT     = (ushort*)(ws + 8782336);   // 32,768 ushorts
    ushort* W0T     = (ushort*)(ws + 8798720);   // 65,536 ushorts
    ushort* W1T     = (ushort*)(ws + 8831488);   // 32,768 ushorts
    float*  out     = (float*)d_out;

    k0b    <<<dim3(384), 512, 0, stream>>>(edges, lin0_w, lin1_w, Ws, W0T, W1T, WsT, binned, offs);
    k1_wh  <<<dim3(1024), 256, 0, stream>>>(X, WsT, a, Whb, w1, w2);
    k2_att <<<dim3(Bx * Ex, Nx / 64), 512, 0, stream>>>(binned, offs, Whb, w1, w2, Hb);
    k3_lin0<<<dim3(512), 256, 0, stream>>>(Hb, W0T, lin0_b, h_pre, partials);
    k3b_stats<<<8, 256, 0, stream>>>(partials, gamma, beta, sb);
    k4_lin1<<<dim3(512), 256, 0, stream>>>(h_pre, sb, W1T, lin1_b, out);
}